// Round 14
// baseline (246.570 us; speedup 1.0000x reference)
//
#include <hip/hip_runtime.h>

typedef unsigned short ushort_t;
typedef unsigned int uint_t;
typedef __bf16 bf16x8 __attribute__((ext_vector_type(8)));
typedef float f32x4 __attribute__((ext_vector_type(4)));
typedef float f32x16 __attribute__((ext_vector_type(16)));
typedef int i32x2 __attribute__((ext_vector_type(2)));

#define DIMD 1024
#define FFD 4096
#define NHEAD 16
#define HDIM 64
#define TLEN 2048
#define BATCH 2
#define MROWS (BATCH * TLEN)  // 4096
#define BHT (BATCH * NHEAD * TLEN)
// 0.125 * log2(e): folds the 1/sqrt(64) scale and exp->exp2 conversion into Q
#define QSCALE 0.18033688011112042f

__device__ __forceinline__ ushort_t f2b(float f) {
    uint_t u = __builtin_bit_cast(uint_t, f);
    u = u + 0x7fffu + ((u >> 16) & 1u);
    return (ushort_t)(u >> 16);
}
__device__ __forceinline__ float b2f(ushort_t b) {
    uint_t u = ((uint_t)b) << 16;
    return __builtin_bit_cast(float, u);
}
__device__ __forceinline__ bf16x8 ld8(const ushort_t* p) {
    uint4 v = *(const uint4*)(p);
    return __builtin_bit_cast(bf16x8, v);
}
__device__ __forceinline__ bf16x8 ld8b(const char* p) {
    uint4 v = *(const uint4*)(p);
    return __builtin_bit_cast(bf16x8, v);
}
__device__ __forceinline__ f32x4 mfma16(bf16x8 a, bf16x8 b, f32x4 c) {
    return __builtin_amdgcn_mfma_f32_16x16x32_bf16(a, b, c, 0, 0, 0);
}
__device__ __forceinline__ f32x16 mfma32(bf16x8 a, bf16x8 b, f32x16 c) {
    return __builtin_amdgcn_mfma_f32_32x32x16_bf16(a, b, c, 0, 0, 0);
}
__device__ __forceinline__ uint_t cvtpk(float lo, float hi) {
    uint_t r;
    asm("v_cvt_pk_bf16_f32 %0, %1, %2" : "=v"(r) : "v"(lo), "v"(hi));
    return r;
}
__device__ __forceinline__ void plswap(uint_t& a, uint_t& b) {
    i32x2 r = __builtin_amdgcn_permlane32_swap((int)a, (int)b, false, false);
    a = (uint_t)r.x;
    b = (uint_t)r.y;
}
__device__ __forceinline__ float exp2a(float x) {
    float r;
    asm("v_exp_f32 %0, %1" : "=v"(r) : "v"(x));
    return r;
}
// tanh-form GELU via single v_exp + v_rcp (max abs err ~3e-4)
__device__ __forceinline__ float gelu_fast(float v) {
    const float u = fmaf(0.044715f * v * v, v, v);
    const float t = exp2a(-2.302118131f * u);
    return v * __builtin_amdgcn_rcpf(1.0f + t);
}
__device__ __forceinline__ void gload16(const void* g, void* l) {
    __builtin_amdgcn_global_load_lds(
        (const __attribute__((address_space(1))) void*)g,
        (__attribute__((address_space(3))) void*)l, 16, 0, 0);
}

// ================= prep: weight transposes + rope tables + bias pack + ln1 =================
__global__ __launch_bounds__(256) void prep_kernel(
    const float* __restrict__ Wq, const float* __restrict__ Wk,
    const float* __restrict__ Wv, const float* __restrict__ Wo,
    const float* __restrict__ W1, const float* __restrict__ W2,
    const float* __restrict__ bq, const float* __restrict__ bk,
    const float* __restrict__ bv,
    ushort_t* __restrict__ wt_qkv, ushort_t* __restrict__ wot,
    ushort_t* __restrict__ w1t, ushort_t* __restrict__ w2t,
    float* __restrict__ cosv, float* __restrict__ sinv,
    float* __restrict__ bias_qkv,
    const float* __restrict__ x, const float* __restrict__ ln1_g,
    const float* __restrict__ ln1_b, ushort_t* __restrict__ n1) {
    __shared__ float tile[32][36];
    __shared__ float rs[4], rq[4];
    const int id = blockIdx.x;
    const int tid = threadIdx.x;
    if (id < 12288) {
        const float* in;
        ushort_t* out;
        int R, C, bx, by;
        if (id < 4096) {
            const int w = id >> 10, loc = id & 1023;
            in = (w == 0) ? Wq : (w == 1) ? Wk : (w == 2) ? Wv : Wo;
            out = (w == 3) ? wot : wt_qkv + (size_t)w * 1024 * 1024;
            R = 1024; C = 1024; bx = loc & 31; by = loc >> 5;
        } else if (id < 8192) {
            const int loc = id - 4096;
            in = W1; out = w1t; R = 1024; C = 4096;
            bx = loc & 127; by = loc >> 7;
        } else {
            const int loc = id - 8192;
            in = W2; out = w2t; R = 4096; C = 1024;
            bx = loc & 31; by = loc >> 5;
        }
        const int c0 = bx * 32, r0 = by * 32;
        const int r = tid >> 3;
        const int c4 = (tid & 7) * 4;
        *(float4*)&tile[r][c4] =
            *(const float4*)&in[(size_t)(r0 + r) * C + c0 + c4];
        __syncthreads();
        const int c = tid >> 3;
        const int rr = (tid & 7) * 4;
        ushort_t o4[4];
#pragma unroll
        for (int j = 0; j < 4; ++j) o4[j] = f2b(tile[rr + j][c]);
        *(uint2*)&out[(size_t)(c0 + c) * R + r0 + rr] = *(uint2*)o4;
    } else if (id < 12544) {
        const int idx = (id - 12288) * 256 + tid;  // T*32
        const int i = idx & 31;
        const int t = idx >> 5;
        const float invf = powf(10000.0f, -(float)i / 32.0f);
        const float a = (float)t * invf;
        cosv[idx] = cosf(a);
        sinv[idx] = sinf(a);
    } else if (id < 12556) {
        const int i = (id - 12544) * 256 + tid;
        if (i < 3072) {
            float v = (i < 1024) ? bq[i] : (i < 2048) ? bk[i - 1024] : bv[i - 2048];
            bias_qkv[i] = v;
        }
    } else {
        // ln1: one row per block
        const int row = id - 12556;
        const float4 v = *(const float4*)(x + (size_t)row * DIMD + tid * 4);
        float s = v.x + v.y + v.z + v.w;
        float sq = v.x * v.x + v.y * v.y + v.z * v.z + v.w * v.w;
#pragma unroll
        for (int off = 1; off < 64; off <<= 1) {
            s += __shfl_xor(s, off);
            sq += __shfl_xor(sq, off);
        }
        const int wave = tid >> 6;
        if ((tid & 63) == 0) { rs[wave] = s; rq[wave] = sq; }
        __syncthreads();
        s = rs[0] + rs[1] + rs[2] + rs[3];
        sq = rq[0] + rq[1] + rq[2] + rq[3];
        const float mean = s * (1.0f / DIMD);
        const float var = sq * (1.0f / DIMD) - mean * mean;
        const float rstd = rsqrtf(var + 1e-5f);
        const float4 gv = *(const float4*)(ln1_g + tid * 4);
        const float4 bv = *(const float4*)(ln1_b + tid * 4);
        ushort_t o[4];
        o[0] = f2b((v.x - mean) * rstd * gv.x + bv.x);
        o[1] = f2b((v.y - mean) * rstd * gv.y + bv.y);
        o[2] = f2b((v.z - mean) * rstd * gv.z + bv.z);
        o[3] = f2b((v.w - mean) * rstd * gv.w + bv.w);
        *(uint2*)(n1 + (size_t)row * DIMD + tid * 4) = *(uint2*)&o[0];
    }
}

// ---------------- layernorm fp32 -> bf16 (ln2) ----------------
__global__ __launch_bounds__(256) void ln_kernel(const float* __restrict__ x,
                                                 const float* __restrict__ g,
                                                 const float* __restrict__ bta,
                                                 ushort_t* __restrict__ out) {
    const int row = blockIdx.x;
    const int tid = threadIdx.x;
    const float4 v = *(const float4*)(x + (size_t)row * DIMD + tid * 4);
    float s = v.x + v.y + v.z + v.w;
    float sq = v.x * v.x + v.y * v.y + v.z * v.z + v.w * v.w;
#pragma unroll
    for (int off = 1; off < 64; off <<= 1) {
        s += __shfl_xor(s, off);
        sq += __shfl_xor(sq, off);
    }
    __shared__ float rs[4], rq[4];
    const int wave = tid >> 6;
    if ((tid & 63) == 0) { rs[wave] = s; rq[wave] = sq; }
    __syncthreads();
    s = rs[0] + rs[1] + rs[2] + rs[3];
    sq = rq[0] + rq[1] + rq[2] + rq[3];
    const float mean = s * (1.0f / DIMD);
    const float var = sq * (1.0f / DIMD) - mean * mean;
    const float rstd = rsqrtf(var + 1e-5f);
    const float4 gv = *(const float4*)(g + tid * 4);
    const float4 bv = *(const float4*)(bta + tid * 4);
    ushort_t o[4];
    o[0] = f2b((v.x - mean) * rstd * gv.x + bv.x);
    o[1] = f2b((v.y - mean) * rstd * gv.y + bv.y);
    o[2] = f2b((v.z - mean) * rstd * gv.z + bv.z);
    o[3] = f2b((v.w - mean) * rstd * gv.w + bv.w);
    *(uint2*)(out + (size_t)row * DIMD + tid * 4) = *(uint2*)&o[0];
}

// ================= GEMM d2 body (m97 structure: 128x128, BK=64, single buffer) =================
template <bool GELU, bool OUTBF16, bool PARTIAL>
__device__ __forceinline__ void gemm_d2_body(
    const ushort_t* __restrict__ A, const ushort_t* __restrict__ Bt,
    const float* __restrict__ bias,
    float* __restrict__ outf, ushort_t* __restrict__ outb,
    int M, int N, int K, int ldk, ushort_t* Asm, ushort_t* Bsm) {
    const int tid = threadIdx.x;
    const int lane = tid & 63;
    const int wave = tid >> 6;
    const int wr = (wave >> 1) * 64;
    const int wc = (wave & 1) * 64;
    const int kz = blockIdx.z;
    A += (size_t)kz * K;
    Bt += (size_t)kz * K;
    ushort_t* outbp = PARTIAL ? outb + (size_t)kz * M * N : outb;
    const int nwg = gridDim.x * gridDim.y;
    const int lin = blockIdx.y * gridDim.x + blockIdx.x;
    const int wg = (lin & 7) * (nwg >> 3) + (lin >> 3);
    const int bm = (wg / gridDim.x) * 128;
    const int bn = (wg % gridDim.x) * 128;
    const int lrow = lane & 15;
    const int lkb = (lane >> 4) << 4;

    const int so = tid * 16;
    const int srow0 = so >> 7;
    const int scolb = (so & 127) ^ ((srow0 & 7) << 4);
    const ushort_t* Ag = A + (size_t)(bm + srow0) * ldk + (scolb >> 1);
    const ushort_t* Bg = Bt + (size_t)(bn + srow0) * ldk + (scolb >> 1);

    f32x4 acc[4][4] = {};
    const int nst = K >> 6;

    for (int t = 0; t < nst; ++t) {
        const int k0 = t << 6;
        __syncthreads();
#pragma unroll
        for (int j = 0; j < 4; ++j) {
            gload16(Ag + (size_t)j * 32 * ldk + k0, (char*)Asm + j * 4096 + so);
            gload16(Bg + (size_t)j * 32 * ldk + k0, (char*)Bsm + j * 4096 + so);
        }
        __syncthreads();
#pragma unroll
        for (int ss = 0; ss < 2; ++ss) {
            bf16x8 af[4], bfr[4];
#pragma unroll
            for (int i = 0; i < 4; ++i) {
                const int r = wr + i * 16 + lrow;
                af[i] = ld8b((char*)Asm + (r << 7) +
                             ((ss * 64 + lkb) ^ ((r & 7) << 4)));
            }
#pragma unroll
            for (int j = 0; j < 4; ++j) {
                const int r = wc + j * 16 + lrow;
                bfr[j] = ld8b((char*)Bsm + (r << 7) +
                              ((ss * 64 + lkb) ^ ((r & 7) << 4)));
            }
            __builtin_amdgcn_s_setprio(1);
#pragma unroll
            for (int i = 0; i < 4; ++i)
#pragma unroll
                for (int j = 0; j < 4; ++j)
                    acc[i][j] = mfma16(af[i], bfr[j], acc[i][j]);
            __builtin_amdgcn_s_setprio(0);
        }
    }

    const int lr4 = (lane >> 4) * 4;
#pragma unroll
    for (int i = 0; i < 4; ++i) {
#pragma unroll
        for (int j = 0; j < 4; ++j) {
            const int col = bn + wc + j * 16 + lrow;
            const float bz = PARTIAL ? 0.0f : bias[col];
#pragma unroll
            for (int q = 0; q < 4; ++q) {
                const int row = bm + wr + i * 16 + lr4 + q;
                float v = acc[i][j][q] + bz;
                if (GELU) v = gelu_fast(v);
                if (OUTBF16)
                    outbp[(size_t)row * N + col] = f2b(v);
                else
                    outf[(size_t)row * N + col] = v;
            }
        }
    }
}

// (256,3): for qkv / ff2 (grids 768 / 512)
template <bool GELU, bool OUTBF16, bool PARTIAL>
__global__ __launch_bounds__(256, 3) void gemm_d2_kernel(
    const ushort_t* __restrict__ A, const ushort_t* __restrict__ Bt,
    const float* __restrict__ bias,
    float* __restrict__ outf, ushort_t* __restrict__ outb,
    int M, int N, int K, int ldk) {
    __shared__ __align__(16) ushort_t Asm[128 * 64];
    __shared__ __align__(16) ushort_t Bsm[128 * 64];
    gemm_d2_body<GELU, OUTBF16, PARTIAL>(A, Bt, bias, outf, outb, M, N, K, ldk,
                                         Asm, Bsm);
}

// (256,4): for ff1 (grid 1024 = exactly 4 blocks/CU). VGPR capped at 128.
template <bool GELU, bool OUTBF16, bool PARTIAL>
__global__ __launch_bounds__(256, 4) void gemm_d2b_kernel(
    const ushort_t* __restrict__ A, const ushort_t* __restrict__ Bt,
    const float* __restrict__ bias,
    float* __restrict__ outf, ushort_t* __restrict__ outb,
    int M, int N, int K, int ldk) {
    __shared__ __align__(16) ushort_t Asm[128 * 64];
    __shared__ __align__(16) ushort_t Bsm[128 * 64];
    gemm_d2_body<GELU, OUTBF16, PARTIAL>(A, Bt, bias, outf, outb, M, N, K, ldk,
                                         Asm, Bsm);
}

// ---------------- ff2 split-K reduce: out = x1 + b2 + sum of 4 bf16 partials ----------------
__global__ __launch_bounds__(256) void ff2_reduce_kernel(
    const ushort_t* __restrict__ parts, const float* __restrict__ x1,
    const float* __restrict__ b2, float* __restrict__ out) {
    const size_t e = ((size_t)blockIdx.x * 256 + threadIdx.x) * 4;
    const size_t np = (size_t)MROWS * DIMD;
    const float4 r = *(const float4*)(x1 + e);
    const float4 bz = *(const float4*)(b2 + (e & (DIMD - 1)));
    float acc[4] = {0.0f, 0.0f, 0.0f, 0.0f};
#pragma unroll
    for (int z = 0; z < 4; ++z) {
        union { uint2 u; ushort_t s[4]; } pv;
        pv.u = *(const uint2*)(parts + z * np + e);
#pragma unroll
        for (int j = 0; j < 4; ++j) acc[j] += b2f(pv.s[j]);
    }
    float4 o;
    o.x = r.x + bz.x + acc[0];
    o.y = r.y + bz.y + acc[1];
    o.z = r.z + bz.z + acc[2];
    o.w = r.w + bz.w + acc[3];
    *(float4*)(out + e) = o;
}

// ================= GEMM p4: 128x64 tile, 4-deep multibuffer (wo-proj) =================
template <bool GELU, bool RES, bool OUTBF16>
__global__ __launch_bounds__(256) void gemm_p4_kernel(
    const ushort_t* __restrict__ A, const ushort_t* __restrict__ Bt,
    const float* __restrict__ bias, const float* __restrict__ res,
    float* __restrict__ outf, ushort_t* __restrict__ outb,
    int M, int N, int K) {
    __shared__ __align__(16) ushort_t Asm[4][128 * 32];
    __shared__ __align__(16) ushort_t Bsm[4][64 * 32];
    const int tid = threadIdx.x;
    const int lane = tid & 63;
    const int wave = tid >> 6;
    const int wm = wave >> 1;
    const int wn = wave & 1;
    const int gx = N >> 6;
    const int nwg = gridDim.x;
    const int lin = blockIdx.x;
    const int wg = (lin & 7) * (nwg >> 3) + (lin >> 3);
    const int bm = (wg / gx) << 7;
    const int bn = (wg % gx) << 6;
    const int lrow = lane & 15;
    const int g = lane >> 4;

    const int r16 = lane >> 2;
    const int scb = (((lane & 3) ^ (r16 & 3)) << 4) >> 1;
    const ushort_t* AgP0 = A + (size_t)(bm + (wave * 2 + 0) * 16 + r16) * K + scb;
    const ushort_t* AgP1 = A + (size_t)(bm + (wave * 2 + 1) * 16 + r16) * K + scb;
    const ushort_t* BgP = Bt + (size_t)(bn + wave * 16 + r16) * K + scb;
    const int dA0 = (wave * 2 + 0) * 1024 + lane * 16;
    const int dA1 = (wave * 2 + 1) * 1024 + lane * 16;
    const int dB = wave * 1024 + lane * 16;

#define P4_STAGE(buf, k0)                            \
    do {                                             \
        gload16(AgP0 + (k0), (char*)Asm[buf] + dA0); \
        gload16(AgP1 + (k0), (char*)Asm[buf] + dA1); \
        gload16(BgP + (k0), (char*)Bsm[buf] + dB);   \
    } while (0)

#define P4_BODY(t)                                                           \
    {                                                                        \
        const int buf = (t) & 3;                                             \
        if ((t) + 3 < nst) P4_STAGE(((t) + 3) & 3, ((t) + 3) << 5);          \
        bf16x8 af[4], bfr[2];                                                \
        _Pragma("unroll") for (int i = 0; i < 4; ++i)                        \
            af[i] = ld8b((char*)Asm[buf] + ((wm * 64 + i * 16 + lrow) << 6) +\
                         ((g * 16) ^ ((lrow & 3) << 4)));                    \
        _Pragma("unroll") for (int j = 0; j < 2; ++j)                        \
            bfr[j] = ld8b((char*)Bsm[buf] + ((wn * 32 + j * 16 + lrow) << 6)+\
                          ((g * 16) ^ ((lrow & 3) << 4)));                   \
        __builtin_amdgcn_s_setprio(1);                                       \
        _Pragma("unroll") for (int i = 0; i < 4; ++i)                        \
        _Pragma("unroll") for (int j = 0; j < 2; ++j)                        \
            acc[i][j] = mfma16(af[i], bfr[j], acc[i][j]);                    \
        __builtin_amdgcn_s_setprio(0);                                       \
    }

    f32x4 acc[4][2] = {};
    const int nst = K >> 5;

    P4_STAGE(0, 0);
    P4_STAGE(1, 32);
    P4_STAGE(2, 64);

    for (int t = 0; t < nst - 2; ++t) {
        asm volatile("s_waitcnt vmcnt(6)" ::: "memory");
        __builtin_amdgcn_s_barrier();
        __builtin_amdgcn_sched_barrier(0);
        P4_BODY(t);
    }
    {
        asm volatile("s_waitcnt vmcnt(3)" ::: "memory");
        __builtin_amdgcn_s_barrier();
        __builtin_amdgcn_sched_barrier(0);
        P4_BODY(nst - 2);
    }
    {
        asm volatile("s_waitcnt vmcnt(0)" ::: "memory");
        __builtin_amdgcn_s_barrier();
        __builtin_amdgcn_sched_barrier(0);
        P4_BODY(nst - 1);
    }
#undef P4_BODY
#undef P4_STAGE

#pragma unroll
    for (int i = 0; i < 4; ++i) {
#pragma unroll
        for (int j = 0; j < 2; ++j) {
#pragma unroll
            for (int q = 0; q < 4; ++q) {
                const int row = bm + wm * 64 + i * 16 + g * 4 + q;
                const int col = bn + wn * 32 + j * 16 + lrow;
                float v = acc[i][j][q] + bias[col];
                if (RES) v += res[(size_t)row * N + col];
                if (GELU) v = gelu_fast(v);
                if (OUTBF16)
                    outb[(size_t)row * N + col] = f2b(v);
                else
                    outf[(size_t)row * N + col] = v;
            }
        }
    }
}

// ================= fused rope-apply + V-transpose =================
__global__ __launch_bounds__(256) void qkv_post_kernel(
    const ushort_t* __restrict__ qkv, const float* __restrict__ cosv,
    const float* __restrict__ sinv, ushort_t* __restrict__ Qb,
    ushort_t* __restrict__ Kb, ushort_t* __restrict__ VtG) {
    __shared__ ushort_t tile[64][72];
    const int bh = blockIdx.y;
    const int b = bh >> 4, h = bh & 15;
    const int t0 = blockIdx.x * 64;
    const int tid = threadIdx.x;
    {
        const int r = tid >> 2;
        const int i0 = (tid & 3) * 8;
        const int t = t0 + r;
        const size_t rowoff = ((size_t)(b * TLEN + t)) * 3072 + h * 64;
        union { uint4 u; ushort_t s[8]; } q1v, q2v, k1v, k2v;
        q1v.u = *(const uint4*)(qkv + rowoff + i0);
        q2v.u = *(const uint4*)(qkv + rowoff + 32 + i0);
        k1v.u = *(const uint4*)(qkv + rowoff + 1024 + i0);
        k2v.u = *(const uint4*)(qkv + rowoff + 1024 + 32 + i0);
        const size_t ooff = ((size_t)bh * TLEN + t) * 64;
        ushort_t oq1[8], oq2[8], ok1[8], ok2[8];
#pragma unroll
        for (int j = 0; j < 8; ++j) {
            const float c = cosv[t * 32 + i0 + j];
            const float s = sinv[t * 32 + i0 + j];
            const float a1 = b2f(q1v.s[j]), a2 = b2f(q2v.s[j]);
            const float c1 = b2f(k1v.s[j]), c2 = b2f(k2v.s[j]);
            oq1[j] = f2b((a1 * c - a2 * s) * QSCALE);
            oq2[j] = f2b((a2 * c + a1 * s) * QSCALE);
            ok1[j] = f2b(c1 * c - c2 * s);
            ok2[j] = f2b(c2 * c + c1 * s);
        }
        *(uint4*)(Qb + ooff + i0) = *(uint4*)oq1;
        *(uint4*)(Qb + ooff + 32 + i0) = *(uint4*)oq2;
        *(uint4*)(Kb + ooff + i0) = *(uint4*)ok1;
        *(uint4*)(Kb + ooff + 32 + i0) = *(uint4*)ok2;
    }
    {
        const int r = tid >> 2;
        const int dp = (tid & 3) * 16;
        const ushort_t* src =
            qkv + (size_t)(b * TLEN + t0 + r) * 3072 + 2048 + h * 64 + dp;
        *(uint4*)&tile[r][dp] = *(const uint4*)src;
        *(uint4*)&tile[r][dp + 8] = *(const uint4*)(src + 8);
        __syncthreads();
        const int d = tid >> 2;
        const int tp = (tid & 3) * 16;
        ushort_t* dst = VtG + (size_t)bh * HDIM * TLEN + (size_t)d * TLEN + t0 + tp;
        ushort_t tmp[16];
#pragma unroll
        for (int j = 0; j < 16; ++j) tmp[j] = tile[tp + j][d];
        *(uint4*)dst = *(uint4*)&tmp[0];
        *(uint4*)(dst + 8) = *(uint4*)&tmp[8];
    }
}

// ---------------- flash attention v10: v9 + l-via-MFMA (ones-A row sum) ----------------
// grid 1024 (XCD-chunked), 256 thr = 4 waves; wave owns 32 q rows; KVBLK=64.
// KV-split-2 additive partials. l computed by mfma32(ones, pB, lacc):
// every row-reg of lacc = sum_k p[k][q], so l = lacc[0], no shuffles/VALU adds.
__global__ __launch_bounds__(256) void flash_kernel(const ushort_t* __restrict__ Qb,
                                                    const ushort_t* __restrict__ Kb,
                                                    const ushort_t* __restrict__ VtG,
                                                    ushort_t* __restrict__ Opart,
                                                    float* __restrict__ Lpart) {
    __shared__ __align__(16) ushort_t Ksm[2][64 * 64];  // [key][d]
    __shared__ __align__(16) ushort_t Vsm[2][64 * 64];  // [d][key]
    const int lin = blockIdx.x;
    const int wg = (lin & 7) * 128 + (lin >> 3);
    const int half = wg & 1;
    const int qblk = (wg >> 1) & 15;
    const int bh = wg >> 5;
    const int b = bh >> 4, h = bh & 15;
    const int lane = threadIdx.x & 63;
    const int wave = threadIdx.x >> 6;
    const int q0 = qblk * 128 + wave * 32;
    const int lq = lane & 31;
    const int hl = lane >> 5;
    const int kb0 = half * (TLEN / 2);

    const ushort_t* Qp = Qb + ((size_t)bh * TLEN + q0) * HDIM;
    const ushort_t* Kp = Kb + (size_t)bh * TLEN * HDIM;
    const ushort_t* Vt = VtG + (size_t)bh * HDIM * TLEN;

    const int ch0 = wave * 2, ch1 = wave * 2 + 1;
    const int so0 = (ch0 << 10) + lane * 16;
    const int so1 = (ch1 << 10) + lane * 16;
    const int sr0 = so0 >> 7, sr1 = so1 >> 7;
    const int cb0 = (so0 & 127) ^ ((sr0 & 7) << 4);
    const int cb1 = (so1 & 127) ^ ((sr1 & 7) << 4);
    const ushort_t* Kg0 = Kp + (size_t)sr0 * HDIM + (cb0 >> 1);
    const ushort_t* Kg1 = Kp + (size_t)sr1 * HDIM + (cb1 >> 1);
    const ushort_t* Vg0 = Vt + (size_t)sr0 * TLEN + (cb0 >> 1);
    const ushort_t* Vg1 = Vt + (size_t)sr1 * TLEN + (cb1 >> 1);

#define FLASH_STAGE(buf, kb)                                               \
    {                                                                      \
        gload16(Kg0 + (size_t)(kb) * HDIM, (char*)Ksm[buf] + (ch0 << 10)); \
        gload16(Kg1 + (size_t)(kb) * HDIM, (char*)Ksm[buf] + (ch1 << 10)); \
        gload16(Vg0 + (kb), (char*)Vsm[buf] + (ch0 << 10));                \
        gload16(Vg1 + (kb), (char*)Vsm[buf] + (ch1 << 10));                \
    }

    bf16x8 qf[4];
#pragma unroll
    for (int c = 0; c < 4; ++c)
        qf[c] = ld8(Qp + lq * 64 + c * 16 + hl * 8);

    // all-ones bf16 A fragment for the l row-sum MFMA
    uint4 ones_u;
    ones_u.x = 0x3f803f80u; ones_u.y = 0x3f803f80u;
    ones_u.z = 0x3f803f80u; ones_u.w = 0x3f803f80u;
    const bf16x8 onesA = __builtin_bit_cast(bf16x8, ones_u);

    f32x16 oacc[2], lacc;
    f32x16 z16;
#pragma unroll
    for (int r = 0; r < 16; ++r) {
        oacc[0][r] = 0.0f; oacc[1][r] = 0.0f; lacc[r] = 0.0f; z16[r] = 0.0f;
    }

    FLASH_STAGE(0, kb0);

    for (int it = 0; it < TLEN / 128; ++it) {
        const int buf = it & 1;
        if (it + 1 < TLEN / 128) {
            FLASH_STAGE(buf ^ 1, kb0 + (it + 1) * 64);
            asm volatile("s_waitcnt vmcnt(4)" ::: "memory");
        } else {
            asm volatile("s_waitcnt vmcnt(0)" ::: "memory");
        }
        __builtin_amdgcn_s_barrier();
        __builtin_amdgcn_sched_barrier(0);

#pragma unroll
        for (int ks2 = 0; ks2 < 2; ++ks2) {
            const int krow = ks2 * 32 + lq;
            const int swk = (krow & 7) << 4;
            const char* kr = (const char*)(Ksm[buf] + krow * 64);
            f32x16 S = z16;
            __builtin_amdgcn_s_setprio(1);
#pragma unroll
            for (int c = 0; c < 4; ++c)
                S = mfma32(ld8b(kr + ((c * 32 + hl * 16) ^ swk)), qf[c], S);
            __builtin_amdgcn_s_setprio(0);
            float p[16];
#pragma unroll
            for (int r = 0; r < 16; ++r) p[r] = exp2a(S[r]);
            uint_t a0 = cvtpk(p[0], p[1]), a1 = cvtpk(p[2], p[3]);
            uint_t b0 = cvtpk(p[4], p[5]), b1 = cvtpk(p[6], p[7]);
            plswap(a0, b0);
            plswap(a1, b1);
            uint4 w0; w0.x = a0; w0.y = a1; w0.z = b0; w0.w = b1;
            a0 = cvtpk(p[8], p[9]);   a1 = cvtpk(p[10], p[11]);
            b0 = cvtpk(p[12], p[13]); b1 = cvtpk(p[14], p[15]);
            plswap(a0, b0);
            plswap(a1, b1);
            uint4 w1; w1.x = a0; w1.y = a1; w1.z = b0; w1.w = b1;
            const bf16x8 pB0 = __builtin_bit_cast(bf16x8, w0);
            const bf16x8 pB1 = __builtin_bit_cast(bf16x8, w1);
            __builtin_amdgcn_s_setprio(1);
            lacc = mfma32(onesA, pB0, lacc);
            lacc = mfma32(onesA, pB1, lacc);
#pragma unroll
            for (int dt = 0; dt < 2; ++dt) {
                const int vrow = dt * 32 + lq;
                const int swv = (vrow & 7) << 4;
                const char* vr = (const char*)(Vsm[buf] + vrow * 64);
                oacc[dt] = mfma32(
                    ld8b(vr + ((ks2 * 64 + hl * 16) ^ swv)), pB0, oacc[dt]);
                oacc[dt] = mfma32(
                    ld8b(vr + ((ks2 * 64 + 32 + hl * 16) ^ swv)), pB1, oacc[dt]);
            }
            __builtin_amdgcn_s_setprio(0);
        }
        __builtin_amdgcn_s_barrier();  // reads consumed; next stage may overwrite
    }
#undef FLASH_STAGE

    const float l = lacc[0];  // every row-reg holds sum_k p[k][q]
    const int qrow = b * TLEN + q0 + lq;
    ushort_t* op = Opart + (size_t)half * MROWS * DIMD + (size_t)qrow * DIMD + h * HDIM;
#pragma unroll
    for (int dt = 0; dt < 2; ++dt) {
#pragma unroll
        for (int qq = 0; qq < 4; ++qq) {
            ushort_t o4[4];
#pragma unroll
            for (int r = 0; r < 4; ++r)
                o4[r] = f2b(oacc[dt][qq * 4 + r]);
            *(uint2*)(op + dt * 32 + qq * 8 + hl * 4) = *(uint2*)&o4[0];
        }
    }
    if (hl == 0)
        Lpart[(size_t)half * BHT + (size_t)bh * TLEN + q0 + lq] = l;
}

// ---------------- attn combine: attn = (O0 + O1) / (l0 + l1) ----------------
__global__ __launch_bounds__(256) void attn_combine_kernel(
    const ushort_t* __restrict__ Opart, const float* __restrict__ Lpart,
    ushort_t* __restrict__ attn) {
    const int idx = blockIdx.x * 256 + threadIdx.x;  // MROWS*DIMD/8 threads
    const int row = idx >> 7;
    const int col = (idx & 127) * 8;
    const int h = col >> 6;
    const int bb = row >> 11;
    const int t = row & (TLEN - 1);
    const int bh = bb * 16 + h;
    const float l = Lpart[(size_t)bh * TLEN + t] +
                    Lpart[(size_t)BHT + (size_t)bh * TLEN + t];
    const float inv = __builtin_amdgcn_rcpf(l);
    const size_t e = (size_t)row * DIMD + col;
    union { uint4 u; ushort_t s[8]; } a, c;
    a.u = *(const uint4*)(Opart + e);
    c.u = *(const uint4*)(Opart + (size_t)MROWS * DIMD + e);
    ushort_t o[8];
#pragma unroll
    for (int j = 0; j < 8; ++j) o[j] = f2b((b2f(a.s[j]) + b2f(c.s[j])) * inv);
    *(uint4*)(attn + e) = *(uint4*)o;
}

extern "C" void kernel_launch(void* const* d_in, const int* in_sizes, int n_in,
                              void* d_out, int out_size, void* d_ws, size_t ws_size,
                              hipStream_t stream) {
    const float* x = (const float*)d_in[0];
    const float* ln1_g = (const float*)d_in[2];
    const float* ln1_b = (const float*)d_in[3];
    const float* Wq = (const float*)d_in[4];
    const float* bq = (const float*)d_in[5];
    const float* Wk = (const float*)d_in[6];
    const float* bk = (const float*)d_in[7];
    const float* Wv = (const float*)d_in[8];
    const float* bv = (const float*)d_in[9];
    const float* Wo = (const float*)d_in[10];
    const float* bo = (const float*)d_in[11];
    const float* ln2_g = (const float*)d_in[12];
    const float* ln2_b = (const float*)d_in[13];
    const float* W1 = (const float*)d_in[14];
    const float* b1 = (const float*)d_in[15];
    const float* W2 = (const float*)d_in[16];
    const float* b2 = (const float*)d_in[17];
    float* out = (float*)d_out;

    char* p = (char*)d_ws;
    ushort_t* wt_qkv = (ushort_t*)p; p += (size_t)3072 * 1024 * 2;
    ushort_t* wot = (ushort_t*)p;    p += (size_t)1024 * 1024 * 2;
    ushort_t* w1t = (ushort_t*)p;    p += (size_t)4096 * 1024 * 2;
    ushort_t* w2t = (ushort_t*)p;    p += (size_t)4096 * 1024 * 2;
    float* cosv = (float*)p;         p += (size_t)TLEN * 32 * 4;
    float* sinv = (float*)p;         p += (size_t)TLEN * 32 * 4;
    float* bias_qkv = (float*)p;     p += 3072 * 4;
    char* reuse0 = p;  // n1+qkv region (33.6MB), time-shared:
                       //   [flash..combine]: Opart (2x8.4MB bf16) + Lpart
                       //   [ff2..reduce]:    bf16 partials (4x8.4MB)
    ushort_t* n1 = (ushort_t*)p;     p += (size_t)MROWS * DIMD * 2;
    ushort_t* qkv = (ushort_t*)p;    p += (size_t)MROWS * 3072 * 2;
    ushort_t* Qb = (ushort_t*)p;     p += (size_t)MROWS * DIMD * 2;
    ushort_t* Kb = (ushort_t*)p;     p += (size_t)MROWS * DIMD * 2;
    ushort_t* VtG = (ushort_t*)p;    p += (size_t)MROWS * DIMD * 2;
    ushort_t* attn = (ushort_t*)p;   p += (size_t)MROWS * DIMD * 2;
    float* x1 = (float*)p;           p += (size_t)MROWS * DIMD * 4;
    ushort_t* n2 = (ushort_t*)p;     p += (size_t)MROWS * DIMD * 2;
    ushort_t* ff1 = (ushort_t*)p;    p += (size_t)MROWS * FFD * 2;
    ushort_t* Opart = (ushort_t*)reuse0;                       // 2 x MROWS x DIMD bf16
    float* Lpart = (float*)(reuse0 + (size_t)2 * MROWS * DIMD * 2);
    ushort_t* partials = (ushort_t*)reuse0;                    // 4 x MROWS x DIMD bf16

    prep_kernel<<<12556 + MROWS, 256, 0, stream>>>(
        Wq, Wk, Wv, Wo, W1, W2, bq, bk, bv, wt_qkv, wot, w1t, w2t, cosv, sinv,
        bias_qkv, x, ln1_g, ln1_b, n1);
    gemm_d2_kernel<false, true, false><<<dim3(3072 / 128, MROWS / 128), 256, 0, stream>>>(
        n1, wt_qkv, bias_qkv, nullptr, qkv, MROWS, 3072, 1024, 1024);
    qkv_post_kernel<<<dim3(TLEN / 64, BATCH * NHEAD), 256, 0, stream>>>(
        qkv, cosv, sinv, Qb, Kb, VtG);
    flash_kernel<<<1024, 256, 0, stream>>>(Qb, Kb, VtG, Opart, Lpart);
    attn_combine_kernel<<<MROWS * DIMD / 8 / 256, 256, 0, stream>>>(Opart, Lpart, attn);
    gemm_p4_kernel<false, true, false><<<512, 256, 0, stream>>>(
        attn, wot, bo, x, x1, nullptr, MROWS, 1024, 1024);
    ln_kernel<<<MROWS, 256, 0, stream>>>(x1, ln2_g, ln2_b, n2);
    gemm_d2b_kernel<true, true, false><<<dim3(4096 / 128, MROWS / 128), 256, 0, stream>>>(
        n2, w1t, b1, nullptr, ff1, MROWS, 4096, 1024, 1024);
    gemm_d2_kernel<false, true, true><<<dim3(1024 / 128, MROWS / 128, 4), 256, 0, stream>>>(
        ff1, w2t, nullptr, nullptr, partials, MROWS, 1024, 1024, 4096);
    ff2_reduce_kernel<<<MROWS * DIMD / 1024, 256, 0, stream>>>(partials, x1, b2, out);
}

// Round 15
// 241.058 us; speedup vs baseline: 1.0229x; 1.0229x over previous
//
#include <hip/hip_runtime.h>

typedef unsigned short ushort_t;
typedef unsigned int uint_t;
typedef __bf16 bf16x8 __attribute__((ext_vector_type(8)));
typedef float f32x4 __attribute__((ext_vector_type(4)));
typedef float f32x16 __attribute__((ext_vector_type(16)));
typedef int i32x2 __attribute__((ext_vector_type(2)));

#define DIMD 1024
#define FFD 4096
#define NHEAD 16
#define HDIM 64
#define TLEN 2048
#define BATCH 2
#define MROWS (BATCH * TLEN)  // 4096
#define BHT (BATCH * NHEAD * TLEN)
// 0.125 * log2(e): folds the 1/sqrt(64) scale and exp->exp2 conversion into Q
#define QSCALE 0.18033688011112042f

__device__ __forceinline__ ushort_t f2b(float f) {
    uint_t u = __builtin_bit_cast(uint_t, f);
    u = u + 0x7fffu + ((u >> 16) & 1u);
    return (ushort_t)(u >> 16);
}
__device__ __forceinline__ float b2f(ushort_t b) {
    uint_t u = ((uint_t)b) << 16;
    return __builtin_bit_cast(float, u);
}
__device__ __forceinline__ bf16x8 ld8(const ushort_t* p) {
    uint4 v = *(const uint4*)(p);
    return __builtin_bit_cast(bf16x8, v);
}
__device__ __forceinline__ bf16x8 ld8b(const char* p) {
    uint4 v = *(const uint4*)(p);
    return __builtin_bit_cast(bf16x8, v);
}
__device__ __forceinline__ f32x4 mfma16(bf16x8 a, bf16x8 b, f32x4 c) {
    return __builtin_amdgcn_mfma_f32_16x16x32_bf16(a, b, c, 0, 0, 0);
}
__device__ __forceinline__ f32x16 mfma32(bf16x8 a, bf16x8 b, f32x16 c) {
    return __builtin_amdgcn_mfma_f32_32x32x16_bf16(a, b, c, 0, 0, 0);
}
__device__ __forceinline__ uint_t cvtpk(float lo, float hi) {
    uint_t r;
    asm("v_cvt_pk_bf16_f32 %0, %1, %2" : "=v"(r) : "v"(lo), "v"(hi));
    return r;
}
__device__ __forceinline__ void plswap(uint_t& a, uint_t& b) {
    i32x2 r = __builtin_amdgcn_permlane32_swap((int)a, (int)b, false, false);
    a = (uint_t)r.x;
    b = (uint_t)r.y;
}
__device__ __forceinline__ float exp2a(float x) {
    float r;
    asm("v_exp_f32 %0, %1" : "=v"(r) : "v"(x));
    return r;
}
// tanh-form GELU via single v_exp + v_rcp (max abs err ~3e-4)
__device__ __forceinline__ float gelu_fast(float v) {
    const float u = fmaf(0.044715f * v * v, v, v);
    const float t = exp2a(-2.302118131f * u);
    return v * __builtin_amdgcn_rcpf(1.0f + t);
}
__device__ __forceinline__ void gload16(const void* g, void* l) {
    __builtin_amdgcn_global_load_lds(
        (const __attribute__((address_space(1))) void*)g,
        (__attribute__((address_space(3))) void*)l, 16, 0, 0);
}

// ================= prep: weight transposes + rope tables + bias pack + ln1 =================
__global__ __launch_bounds__(256) void prep_kernel(
    const float* __restrict__ Wq, const float* __restrict__ Wk,
    const float* __restrict__ Wv, const float* __restrict__ Wo,
    const float* __restrict__ W1, const float* __restrict__ W2,
    const float* __restrict__ bq, const float* __restrict__ bk,
    const float* __restrict__ bv,
    ushort_t* __restrict__ wt_qkv, ushort_t* __restrict__ wot,
    ushort_t* __restrict__ w1t, ushort_t* __restrict__ w2t,
    float* __restrict__ cosv, float* __restrict__ sinv,
    float* __restrict__ bias_qkv,
    const float* __restrict__ x, const float* __restrict__ ln1_g,
    const float* __restrict__ ln1_b, ushort_t* __restrict__ n1) {
    __shared__ float tile[32][36];
    __shared__ float rs[4], rq[4];
    const int id = blockIdx.x;
    const int tid = threadIdx.x;
    if (id < 12288) {
        const float* in;
        ushort_t* out;
        int R, C, bx, by;
        if (id < 4096) {
            const int w = id >> 10, loc = id & 1023;
            in = (w == 0) ? Wq : (w == 1) ? Wk : (w == 2) ? Wv : Wo;
            out = (w == 3) ? wot : wt_qkv + (size_t)w * 1024 * 1024;
            R = 1024; C = 1024; bx = loc & 31; by = loc >> 5;
        } else if (id < 8192) {
            const int loc = id - 4096;
            in = W1; out = w1t; R = 1024; C = 4096;
            bx = loc & 127; by = loc >> 7;
        } else {
            const int loc = id - 8192;
            in = W2; out = w2t; R = 4096; C = 1024;
            bx = loc & 31; by = loc >> 5;
        }
        const int c0 = bx * 32, r0 = by * 32;
        // phase 1: vectorized float4 reads (coalesced along C)
        const int r = tid >> 3;         // 0..31
        const int c4 = (tid & 7) * 4;   // 0,4,...,28
        *(float4*)&tile[r][c4] =
            *(const float4*)&in[(size_t)(r0 + r) * C + c0 + c4];
        __syncthreads();
        // phase 2: ushort4 writes (coalesced along R)
        const int c = tid >> 3;         // 0..31
        const int rr = (tid & 7) * 4;   // 0,4,...,28
        ushort_t o4[4];
#pragma unroll
        for (int j = 0; j < 4; ++j) o4[j] = f2b(tile[rr + j][c]);
        *(uint2*)&out[(size_t)(c0 + c) * R + r0 + rr] = *(uint2*)o4;
    } else if (id < 12544) {
        const int idx = (id - 12288) * 256 + tid;  // T*32
        const int i = idx & 31;
        const int t = idx >> 5;
        const float invf = powf(10000.0f, -(float)i / 32.0f);
        const float a = (float)t * invf;
        cosv[idx] = cosf(a);
        sinv[idx] = sinf(a);
    } else if (id < 12556) {
        const int i = (id - 12544) * 256 + tid;
        if (i < 3072) {
            float v = (i < 1024) ? bq[i] : (i < 2048) ? bk[i - 1024] : bv[i - 2048];
            bias_qkv[i] = v;
        }
    } else {
        // ln1: one row per block
        const int row = id - 12556;
        const float4 v = *(const float4*)(x + (size_t)row * DIMD + tid * 4);
        float s = v.x + v.y + v.z + v.w;
        float sq = v.x * v.x + v.y * v.y + v.z * v.z + v.w * v.w;
#pragma unroll
        for (int off = 1; off < 64; off <<= 1) {
            s += __shfl_xor(s, off);
            sq += __shfl_xor(sq, off);
        }
        const int wave = tid >> 6;
        if ((tid & 63) == 0) { rs[wave] = s; rq[wave] = sq; }
        __syncthreads();
        s = rs[0] + rs[1] + rs[2] + rs[3];
        sq = rq[0] + rq[1] + rq[2] + rq[3];
        const float mean = s * (1.0f / DIMD);
        const float var = sq * (1.0f / DIMD) - mean * mean;
        const float rstd = rsqrtf(var + 1e-5f);
        const float4 gv = *(const float4*)(ln1_g + tid * 4);
        const float4 bv = *(const float4*)(ln1_b + tid * 4);
        ushort_t o[4];
        o[0] = f2b((v.x - mean) * rstd * gv.x + bv.x);
        o[1] = f2b((v.y - mean) * rstd * gv.y + bv.y);
        o[2] = f2b((v.z - mean) * rstd * gv.z + bv.z);
        o[3] = f2b((v.w - mean) * rstd * gv.w + bv.w);
        *(uint2*)(n1 + (size_t)row * DIMD + tid * 4) = *(uint2*)&o[0];
    }
}

// ---------------- layernorm fp32 -> bf16 (ln2) ----------------
__global__ __launch_bounds__(256) void ln_kernel(const float* __restrict__ x,
                                                 const float* __restrict__ g,
                                                 const float* __restrict__ bta,
                                                 ushort_t* __restrict__ out) {
    const int row = blockIdx.x;
    const int tid = threadIdx.x;
    const float4 v = *(const float4*)(x + (size_t)row * DIMD + tid * 4);
    float s = v.x + v.y + v.z + v.w;
    float sq = v.x * v.x + v.y * v.y + v.z * v.z + v.w * v.w;
#pragma unroll
    for (int off = 1; off < 64; off <<= 1) {
        s += __shfl_xor(s, off);
        sq += __shfl_xor(sq, off);
    }
    __shared__ float rs[4], rq[4];
    const int wave = tid >> 6;
    if ((tid & 63) == 0) { rs[wave] = s; rq[wave] = sq; }
    __syncthreads();
    s = rs[0] + rs[1] + rs[2] + rs[3];
    sq = rq[0] + rq[1] + rq[2] + rq[3];
    const float mean = s * (1.0f / DIMD);
    const float var = sq * (1.0f / DIMD) - mean * mean;
    const float rstd = rsqrtf(var + 1e-5f);
    const float4 gv = *(const float4*)(g + tid * 4);
    const float4 bv = *(const float4*)(bta + tid * 4);
    ushort_t o[4];
    o[0] = f2b((v.x - mean) * rstd * gv.x + bv.x);
    o[1] = f2b((v.y - mean) * rstd * gv.y + bv.y);
    o[2] = f2b((v.z - mean) * rstd * gv.z + bv.z);
    o[3] = f2b((v.w - mean) * rstd * gv.w + bv.w);
    *(uint2*)(out + (size_t)row * DIMD + tid * 4) = *(uint2*)&o[0];
}

// ================= GEMM d2: m97 structure (128x128, BK=64, 3 blocks/CU) =================
template <bool GELU, bool OUTBF16, bool PARTIAL>
__global__ __launch_bounds__(256, 3) void gemm_d2_kernel(
    const ushort_t* __restrict__ A, const ushort_t* __restrict__ Bt,
    const float* __restrict__ bias,
    float* __restrict__ outf, ushort_t* __restrict__ outb,
    int M, int N, int K, int ldk) {
    __shared__ __align__(16) ushort_t Asm[128 * 64];
    __shared__ __align__(16) ushort_t Bsm[128 * 64];
    const int tid = threadIdx.x;
    const int lane = tid & 63;
    const int wave = tid >> 6;
    const int wr = (wave >> 1) * 64;
    const int wc = (wave & 1) * 64;
    const int kz = blockIdx.z;
    A += (size_t)kz * K;
    Bt += (size_t)kz * K;
    ushort_t* outbp = PARTIAL ? outb + (size_t)kz * M * N : outb;
    const int nwg = gridDim.x * gridDim.y;
    const int lin = blockIdx.y * gridDim.x + blockIdx.x;
    const int wg = (lin & 7) * (nwg >> 3) + (lin >> 3);
    const int bm = (wg / gridDim.x) * 128;
    const int bn = (wg % gridDim.x) * 128;
    const int lrow = lane & 15;
    const int lkb = (lane >> 4) << 4;

    const int so = tid * 16;
    const int srow0 = so >> 7;
    const int scolb = (so & 127) ^ ((srow0 & 7) << 4);
    const ushort_t* Ag = A + (size_t)(bm + srow0) * ldk + (scolb >> 1);
    const ushort_t* Bg = Bt + (size_t)(bn + srow0) * ldk + (scolb >> 1);

    f32x4 acc[4][4] = {};
    const int nst = K >> 6;

    for (int t = 0; t < nst; ++t) {
        const int k0 = t << 6;
        __syncthreads();
#pragma unroll
        for (int j = 0; j < 4; ++j) {
            gload16(Ag + (size_t)j * 32 * ldk + k0, (char*)Asm + j * 4096 + so);
            gload16(Bg + (size_t)j * 32 * ldk + k0, (char*)Bsm + j * 4096 + so);
        }
        __syncthreads();
#pragma unroll
        for (int ss = 0; ss < 2; ++ss) {
            bf16x8 af[4], bfr[4];
#pragma unroll
            for (int i = 0; i < 4; ++i) {
                const int r = wr + i * 16 + lrow;
                af[i] = ld8b((char*)Asm + (r << 7) +
                             ((ss * 64 + lkb) ^ ((r & 7) << 4)));
            }
#pragma unroll
            for (int j = 0; j < 4; ++j) {
                const int r = wc + j * 16 + lrow;
                bfr[j] = ld8b((char*)Bsm + (r << 7) +
                              ((ss * 64 + lkb) ^ ((r & 7) << 4)));
            }
            __builtin_amdgcn_s_setprio(1);
#pragma unroll
            for (int i = 0; i < 4; ++i)
#pragma unroll
                for (int j = 0; j < 4; ++j)
                    acc[i][j] = mfma16(af[i], bfr[j], acc[i][j]);
            __builtin_amdgcn_s_setprio(0);
        }
    }

    const int lr4 = (lane >> 4) * 4;
#pragma unroll
    for (int i = 0; i < 4; ++i) {
#pragma unroll
        for (int j = 0; j < 4; ++j) {
            const int col = bn + wc + j * 16 + lrow;
            const float bz = PARTIAL ? 0.0f : bias[col];
#pragma unroll
            for (int q = 0; q < 4; ++q) {
                const int row = bm + wr + i * 16 + lr4 + q;
                float v = acc[i][j][q] + bz;
                if (GELU) v = gelu_fast(v);
                if (OUTBF16)
                    outbp[(size_t)row * N + col] = f2b(v);
                else
                    outf[(size_t)row * N + col] = v;
            }
        }
    }
}

// ---------------- ff2 split-K reduce: out = x1 + b2 + sum of 4 bf16 partials ----------------
__global__ __launch_bounds__(256) void ff2_reduce_kernel(
    const ushort_t* __restrict__ parts, const float* __restrict__ x1,
    const float* __restrict__ b2, float* __restrict__ out) {
    const size_t e = ((size_t)blockIdx.x * 256 + threadIdx.x) * 4;
    const size_t np = (size_t)MROWS * DIMD;
    const float4 r = *(const float4*)(x1 + e);
    const float4 bz = *(const float4*)(b2 + (e & (DIMD - 1)));
    float acc[4] = {0.0f, 0.0f, 0.0f, 0.0f};
#pragma unroll
    for (int z = 0; z < 4; ++z) {
        union { uint2 u; ushort_t s[4]; } pv;
        pv.u = *(const uint2*)(parts + z * np + e);
#pragma unroll
        for (int j = 0; j < 4; ++j) acc[j] += b2f(pv.s[j]);
    }
    float4 o;
    o.x = r.x + bz.x + acc[0];
    o.y = r.y + bz.y + acc[1];
    o.z = r.z + bz.z + acc[2];
    o.w = r.w + bz.w + acc[3];
    *(float4*)(out + e) = o;
}

// ================= GEMM p4: 128x64 tile, 4-deep multibuffer (wo-proj) =================
template <bool GELU, bool RES, bool OUTBF16>
__global__ __launch_bounds__(256) void gemm_p4_kernel(
    const ushort_t* __restrict__ A, const ushort_t* __restrict__ Bt,
    const float* __restrict__ bias, const float* __restrict__ res,
    float* __restrict__ outf, ushort_t* __restrict__ outb,
    int M, int N, int K) {
    __shared__ __align__(16) ushort_t Asm[4][128 * 32];
    __shared__ __align__(16) ushort_t Bsm[4][64 * 32];
    const int tid = threadIdx.x;
    const int lane = tid & 63;
    const int wave = tid >> 6;
    const int wm = wave >> 1;
    const int wn = wave & 1;
    const int gx = N >> 6;
    const int nwg = gridDim.x;
    const int lin = blockIdx.x;
    const int wg = (lin & 7) * (nwg >> 3) + (lin >> 3);
    const int bm = (wg / gx) << 7;
    const int bn = (wg % gx) << 6;
    const int lrow = lane & 15;
    const int g = lane >> 4;

    const int r16 = lane >> 2;
    const int scb = (((lane & 3) ^ (r16 & 3)) << 4) >> 1;
    const ushort_t* AgP0 = A + (size_t)(bm + (wave * 2 + 0) * 16 + r16) * K + scb;
    const ushort_t* AgP1 = A + (size_t)(bm + (wave * 2 + 1) * 16 + r16) * K + scb;
    const ushort_t* BgP = Bt + (size_t)(bn + wave * 16 + r16) * K + scb;
    const int dA0 = (wave * 2 + 0) * 1024 + lane * 16;
    const int dA1 = (wave * 2 + 1) * 1024 + lane * 16;
    const int dB = wave * 1024 + lane * 16;

#define P4_STAGE(buf, k0)                            \
    do {                                             \
        gload16(AgP0 + (k0), (char*)Asm[buf] + dA0); \
        gload16(AgP1 + (k0), (char*)Asm[buf] + dA1); \
        gload16(BgP + (k0), (char*)Bsm[buf] + dB);   \
    } while (0)

#define P4_BODY(t)                                                           \
    {                                                                        \
        const int buf = (t) & 3;                                             \
        if ((t) + 3 < nst) P4_STAGE(((t) + 3) & 3, ((t) + 3) << 5);          \
        bf16x8 af[4], bfr[2];                                                \
        _Pragma("unroll") for (int i = 0; i < 4; ++i)                        \
            af[i] = ld8b((char*)Asm[buf] + ((wm * 64 + i * 16 + lrow) << 6) +\
                         ((g * 16) ^ ((lrow & 3) << 4)));                    \
        _Pragma("unroll") for (int j = 0; j < 2; ++j)                        \
            bfr[j] = ld8b((char*)Bsm[buf] + ((wn * 32 + j * 16 + lrow) << 6)+\
                          ((g * 16) ^ ((lrow & 3) << 4)));                   \
        __builtin_amdgcn_s_setprio(1);                                       \
        _Pragma("unroll") for (int i = 0; i < 4; ++i)                        \
        _Pragma("unroll") for (int j = 0; j < 2; ++j)                        \
            acc[i][j] = mfma16(af[i], bfr[j], acc[i][j]);                    \
        __builtin_amdgcn_s_setprio(0);                                       \
    }

    f32x4 acc[4][2] = {};
    const int nst = K >> 5;

    P4_STAGE(0, 0);
    P4_STAGE(1, 32);
    P4_STAGE(2, 64);

    for (int t = 0; t < nst - 2; ++t) {
        asm volatile("s_waitcnt vmcnt(6)" ::: "memory");
        __builtin_amdgcn_s_barrier();
        __builtin_amdgcn_sched_barrier(0);
        P4_BODY(t);
    }
    {
        asm volatile("s_waitcnt vmcnt(3)" ::: "memory");
        __builtin_amdgcn_s_barrier();
        __builtin_amdgcn_sched_barrier(0);
        P4_BODY(nst - 2);
    }
    {
        asm volatile("s_waitcnt vmcnt(0)" ::: "memory");
        __builtin_amdgcn_s_barrier();
        __builtin_amdgcn_sched_barrier(0);
        P4_BODY(nst - 1);
    }
#undef P4_BODY
#undef P4_STAGE

#pragma unroll
    for (int i = 0; i < 4; ++i) {
#pragma unroll
        for (int j = 0; j < 2; ++j) {
#pragma unroll
            for (int q = 0; q < 4; ++q) {
                const int row = bm + wm * 64 + i * 16 + g * 4 + q;
                const int col = bn + wn * 32 + j * 16 + lrow;
                float v = acc[i][j][q] + bias[col];
                if (RES) v += res[(size_t)row * N + col];
                if (GELU) v = gelu_fast(v);
                if (OUTBF16)
                    outb[(size_t)row * N + col] = f2b(v);
                else
                    outf[(size_t)row * N + col] = v;
            }
        }
    }
}

// ================= fused rope-apply + V-transpose =================
__global__ __launch_bounds__(256) void qkv_post_kernel(
    const ushort_t* __restrict__ qkv, const float* __restrict__ cosv,
    const float* __restrict__ sinv, ushort_t* __restrict__ Qb,
    ushort_t* __restrict__ Kb, ushort_t* __restrict__ VtG) {
    __shared__ ushort_t tile[64][72];
    const int bh = blockIdx.y;
    const int b = bh >> 4, h = bh & 15;
    const int t0 = blockIdx.x * 64;
    const int tid = threadIdx.x;
    {
        const int r = tid >> 2;
        const int i0 = (tid & 3) * 8;
        const int t = t0 + r;
        const size_t rowoff = ((size_t)(b * TLEN + t)) * 3072 + h * 64;
        union { uint4 u; ushort_t s[8]; } q1v, q2v, k1v, k2v;
        q1v.u = *(const uint4*)(qkv + rowoff + i0);
        q2v.u = *(const uint4*)(qkv + rowoff + 32 + i0);
        k1v.u = *(const uint4*)(qkv + rowoff + 1024 + i0);
        k2v.u = *(const uint4*)(qkv + rowoff + 1024 + 32 + i0);
        const size_t ooff = ((size_t)bh * TLEN + t) * 64;
        ushort_t oq1[8], oq2[8], ok1[8], ok2[8];
#pragma unroll
        for (int j = 0; j < 8; ++j) {
            const float c = cosv[t * 32 + i0 + j];
            const float s = sinv[t * 32 + i0 + j];
            const float a1 = b2f(q1v.s[j]), a2 = b2f(q2v.s[j]);
            const float c1 = b2f(k1v.s[j]), c2 = b2f(k2v.s[j]);
            oq1[j] = f2b((a1 * c - a2 * s) * QSCALE);
            oq2[j] = f2b((a2 * c + a1 * s) * QSCALE);
            ok1[j] = f2b(c1 * c - c2 * s);
            ok2[j] = f2b(c2 * c + c1 * s);
        }
        *(uint4*)(Qb + ooff + i0) = *(uint4*)oq1;
        *(uint4*)(Qb + ooff + 32 + i0) = *(uint4*)oq2;
        *(uint4*)(Kb + ooff + i0) = *(uint4*)ok1;
        *(uint4*)(Kb + ooff + 32 + i0) = *(uint4*)ok2;
    }
    {
        const int r = tid >> 2;
        const int dp = (tid & 3) * 16;
        const ushort_t* src =
            qkv + (size_t)(b * TLEN + t0 + r) * 3072 + 2048 + h * 64 + dp;
        *(uint4*)&tile[r][dp] = *(const uint4*)src;
        *(uint4*)&tile[r][dp + 8] = *(const uint4*)(src + 8);
        __syncthreads();
        const int d = tid >> 2;
        const int tp = (tid & 3) * 16;
        ushort_t* dst = VtG + (size_t)bh * HDIM * TLEN + (size_t)d * TLEN + t0 + tp;
        ushort_t tmp[16];
#pragma unroll
        for (int j = 0; j < 16; ++j) tmp[j] = tile[tp + j][d];
        *(uint4*)dst = *(uint4*)&tmp[0];
        *(uint4*)(dst + 8) = *(uint4*)&tmp[8];
    }
}

// ---------------- flash attention v9: counted-vmcnt double-barrier (best config) ----------------
// grid 1024 (XCD-chunked), 256 thr = 4 waves; wave owns 32 q rows; KVBLK=64.
// KV-split-2 additive partials. Stage loads (4/wave) stay in flight across
// barriers; vmcnt(4) after issuing next stage = previous stage retired.
__global__ __launch_bounds__(256) void flash_kernel(const ushort_t* __restrict__ Qb,
                                                    const ushort_t* __restrict__ Kb,
                                                    const ushort_t* __restrict__ VtG,
                                                    ushort_t* __restrict__ Opart,
                                                    float* __restrict__ Lpart) {
    __shared__ __align__(16) ushort_t Ksm[2][64 * 64];  // [key][d]
    __shared__ __align__(16) ushort_t Vsm[2][64 * 64];  // [d][key]
    const int lin = blockIdx.x;
    const int wg = (lin & 7) * 128 + (lin >> 3);
    const int half = wg & 1;
    const int qblk = (wg >> 1) & 15;
    const int bh = wg >> 5;
    const int b = bh >> 4, h = bh & 15;
    const int lane = threadIdx.x & 63;
    const int wave = threadIdx.x >> 6;
    const int q0 = qblk * 128 + wave * 32;
    const int lq = lane & 31;
    const int hl = lane >> 5;
    const int kb0 = half * (TLEN / 2);

    const ushort_t* Qp = Qb + ((size_t)bh * TLEN + q0) * HDIM;
    const ushort_t* Kp = Kb + (size_t)bh * TLEN * HDIM;
    const ushort_t* Vt = VtG + (size_t)bh * HDIM * TLEN;

    const int ch0 = wave * 2, ch1 = wave * 2 + 1;
    const int so0 = (ch0 << 10) + lane * 16;
    const int so1 = (ch1 << 10) + lane * 16;
    const int sr0 = so0 >> 7, sr1 = so1 >> 7;
    const int cb0 = (so0 & 127) ^ ((sr0 & 7) << 4);
    const int cb1 = (so1 & 127) ^ ((sr1 & 7) << 4);
    const ushort_t* Kg0 = Kp + (size_t)sr0 * HDIM + (cb0 >> 1);
    const ushort_t* Kg1 = Kp + (size_t)sr1 * HDIM + (cb1 >> 1);
    const ushort_t* Vg0 = Vt + (size_t)sr0 * TLEN + (cb0 >> 1);
    const ushort_t* Vg1 = Vt + (size_t)sr1 * TLEN + (cb1 >> 1);

#define FLASH_STAGE(buf, kb)                                               \
    {                                                                      \
        gload16(Kg0 + (size_t)(kb) * HDIM, (char*)Ksm[buf] + (ch0 << 10)); \
        gload16(Kg1 + (size_t)(kb) * HDIM, (char*)Ksm[buf] + (ch1 << 10)); \
        gload16(Vg0 + (kb), (char*)Vsm[buf] + (ch0 << 10));                \
        gload16(Vg1 + (kb), (char*)Vsm[buf] + (ch1 << 10));                \
    }

    bf16x8 qf[4];
#pragma unroll
    for (int c = 0; c < 4; ++c)
        qf[c] = ld8(Qp + lq * 64 + c * 16 + hl * 8);

    f32x16 oacc[2];
    f32x16 z16;
#pragma unroll
    for (int r = 0; r < 16; ++r) { oacc[0][r] = 0.0f; oacc[1][r] = 0.0f; z16[r] = 0.0f; }
    float ls = 0.0f;

    FLASH_STAGE(0, kb0);

    for (int it = 0; it < TLEN / 128; ++it) {
        const int buf = it & 1;
        if (it + 1 < TLEN / 128) {
            FLASH_STAGE(buf ^ 1, kb0 + (it + 1) * 64);
            asm volatile("s_waitcnt vmcnt(4)" ::: "memory");
        } else {
            asm volatile("s_waitcnt vmcnt(0)" ::: "memory");
        }
        __builtin_amdgcn_s_barrier();
        __builtin_amdgcn_sched_barrier(0);

#pragma unroll
        for (int ks2 = 0; ks2 < 2; ++ks2) {
            const int krow = ks2 * 32 + lq;
            const int swk = (krow & 7) << 4;
            const char* kr = (const char*)(Ksm[buf] + krow * 64);
            f32x16 S = z16;
            __builtin_amdgcn_s_setprio(1);
#pragma unroll
            for (int c = 0; c < 4; ++c)
                S = mfma32(ld8b(kr + ((c * 32 + hl * 16) ^ swk)), qf[c], S);
            __builtin_amdgcn_s_setprio(0);
            float p[16];
#pragma unroll
            for (int r = 0; r < 16; ++r) p[r] = exp2a(S[r]);
#pragma unroll
            for (int r = 0; r < 16; ++r) ls += p[r];
            uint_t a0 = cvtpk(p[0], p[1]), a1 = cvtpk(p[2], p[3]);
            uint_t b0 = cvtpk(p[4], p[5]), b1 = cvtpk(p[6], p[7]);
            plswap(a0, b0);
            plswap(a1, b1);
            uint4 w0; w0.x = a0; w0.y = a1; w0.z = b0; w0.w = b1;
            a0 = cvtpk(p[8], p[9]);   a1 = cvtpk(p[10], p[11]);
            b0 = cvtpk(p[12], p[13]); b1 = cvtpk(p[14], p[15]);
            plswap(a0, b0);
            plswap(a1, b1);
            uint4 w1; w1.x = a0; w1.y = a1; w1.z = b0; w1.w = b1;
            const bf16x8 pB0 = __builtin_bit_cast(bf16x8, w0);
            const bf16x8 pB1 = __builtin_bit_cast(bf16x8, w1);
            __builtin_amdgcn_s_setprio(1);
#pragma unroll
            for (int dt = 0; dt < 2; ++dt) {
                const int vrow = dt * 32 + lq;
                const int swv = (vrow & 7) << 4;
                const char* vr = (const char*)(Vsm[buf] + vrow * 64);
                oacc[dt] = mfma32(
                    ld8b(vr + ((ks2 * 64 + hl * 16) ^ swv)), pB0, oacc[dt]);
                oacc[dt] = mfma32(
                    ld8b(vr + ((ks2 * 64 + 32 + hl * 16) ^ swv)), pB1, oacc[dt]);
            }
            __builtin_amdgcn_s_setprio(0);
        }
        __builtin_amdgcn_s_barrier();  // reads consumed; next stage may overwrite
    }
#undef FLASH_STAGE

    const float l = ls + __shfl_xor(ls, 32);
    const int qrow = b * TLEN + q0 + lq;
    ushort_t* op = Opart + (size_t)half * MROWS * DIMD + (size_t)qrow * DIMD + h * HDIM;
#pragma unroll
    for (int dt = 0; dt < 2; ++dt) {
#pragma unroll
        for (int qq = 0; qq < 4; ++qq) {
            ushort_t o4[4];
#pragma unroll
            for (int r = 0; r < 4; ++r)
                o4[r] = f2b(oacc[dt][qq * 4 + r]);
            *(uint2*)(op + dt * 32 + qq * 8 + hl * 4) = *(uint2*)&o4[0];
        }
    }
    if (hl == 0)
        Lpart[(size_t)half * BHT + (size_t)bh * TLEN + q0 + lq] = l;
}

// ---------------- attn combine: attn = (O0 + O1) / (l0 + l1) ----------------
__global__ __launch_bounds__(256) void attn_combine_kernel(
    const ushort_t* __restrict__ Opart, const float* __restrict__ Lpart,
    ushort_t* __restrict__ attn) {
    const int idx = blockIdx.x * 256 + threadIdx.x;  // MROWS*DIMD/8 threads
    const int row = idx >> 7;
    const int col = (idx & 127) * 8;
    const int h = col >> 6;
    const int bb = row >> 11;
    const int t = row & (TLEN - 1);
    const int bh = bb * 16 + h;
    const float l = Lpart[(size_t)bh * TLEN + t] +
                    Lpart[(size_t)BHT + (size_t)bh * TLEN + t];
    const float inv = __builtin_amdgcn_rcpf(l);
    const size_t e = (size_t)row * DIMD + col;
    union { uint4 u; ushort_t s[8]; } a, c;
    a.u = *(const uint4*)(Opart + e);
    c.u = *(const uint4*)(Opart + (size_t)MROWS * DIMD + e);
    ushort_t o[8];
#pragma unroll
    for (int j = 0; j < 8; ++j) o[j] = f2b((b2f(a.s[j]) + b2f(c.s[j])) * inv);
    *(uint4*)(attn + e) = *(uint4*)o;
}

extern "C" void kernel_launch(void* const* d_in, const int* in_sizes, int n_in,
                              void* d_out, int out_size, void* d_ws, size_t ws_size,
                              hipStream_t stream) {
    const float* x = (const float*)d_in[0];
    const float* ln1_g = (const float*)d_in[2];
    const float* ln1_b = (const float*)d_in[3];
    const float* Wq = (const float*)d_in[4];
    const float* bq = (const float*)d_in[5];
    const float* Wk = (const float*)d_in[6];
    const float* bk = (const float*)d_in[7];
    const float* Wv = (const float*)d_in[8];
    const float* bv = (const float*)d_in[9];
    const float* Wo = (const float*)d_in[10];
    const float* bo = (const float*)d_in[11];
    const float* ln2_g = (const float*)d_in[12];
    const float* ln2_b = (const float*)d_in[13];
    const float* W1 = (const float*)d_in[14];
    const float* b1 = (const float*)d_in[15];
    const float* W2 = (const float*)d_in[16];
    const float* b2 = (const float*)d_in[17];
    float* out = (float*)d_out;

    char* p = (char*)d_ws;
    ushort_t* wt_qkv = (ushort_t*)p; p += (size_t)3072 * 1024 * 2;
    ushort_t* wot = (ushort_t*)p;    p += (size_t)1024 * 1024 * 2;
    ushort_t* w1t = (ushort_t*)p;    p += (size_t)4096 * 1024 * 2;
    ushort_t* w2t = (ushort_t*)p;    p += (size_t)4096 * 1024 * 2;
    float* cosv = (float*)p;         p += (size_t)TLEN * 32 * 4;
    float* sinv = (float*)p;         p += (size_t)TLEN * 32 * 4;
    float* bias_qkv = (float*)p;     p += 3072 * 4;
    char* reuse0 = p;  // n1+qkv region (33.6MB), time-shared:
                       //   [flash..combine]: Opart (2x8.4MB bf16) + Lpart
                       //   [ff2..reduce]:    bf16 partials (4x8.4MB)
    ushort_t* n1 = (ushort_t*)p;     p += (size_t)MROWS * DIMD * 2;
    ushort_t* qkv = (ushort_t*)p;    p += (size_t)MROWS * 3072 * 2;
    ushort_t* Qb = (ushort_t*)p;     p += (size_t)MROWS * DIMD * 2;
    ushort_t* Kb = (ushort_t*)p;     p += (size_t)MROWS * DIMD * 2;
    ushort_t* VtG = (ushort_t*)p;    p += (size_t)MROWS * DIMD * 2;
    ushort_t* attn = (ushort_t*)p;   p += (size_t)MROWS * DIMD * 2;
    float* x1 = (float*)p;           p += (size_t)MROWS * DIMD * 4;
    ushort_t* n2 = (ushort_t*)p;     p += (size_t)MROWS * DIMD * 2;
    ushort_t* ff1 = (ushort_t*)p;    p += (size_t)MROWS * FFD * 2;
    ushort_t* Opart = (ushort_t*)reuse0;                       // 2 x MROWS x DIMD bf16
    float* Lpart = (float*)(reuse0 + (size_t)2 * MROWS * DIMD * 2);
    ushort_t* partials = (ushort_t*)reuse0;                    // 4 x MROWS x DIMD bf16

    prep_kernel<<<12556 + MROWS, 256, 0, stream>>>(
        Wq, Wk, Wv, Wo, W1, W2, bq, bk, bv, wt_qkv, wot, w1t, w2t, cosv, sinv,
        bias_qkv, x, ln1_g, ln1_b, n1);
    gemm_d2_kernel<false, true, false><<<dim3(3072 / 128, MROWS / 128), 256, 0, stream>>>(
        n1, wt_qkv, bias_qkv, nullptr, qkv, MROWS, 3072, 1024, 1024);
    qkv_post_kernel<<<dim3(TLEN / 64, BATCH * NHEAD), 256, 0, stream>>>(
        qkv, cosv, sinv, Qb, Kb, VtG);
    flash_kernel<<<1024, 256, 0, stream>>>(Qb, Kb, VtG, Opart, Lpart);
    attn_combine_kernel<<<MROWS * DIMD / 8 / 256, 256, 0, stream>>>(Opart, Lpart, attn);
    gemm_p4_kernel<false, true, false><<<512, 256, 0, stream>>>(
        attn, wot, bo, x, x1, nullptr, MROWS, 1024, 1024);
    ln_kernel<<<MROWS, 256, 0, stream>>>(x1, ln2_g, ln2_b, n2);
    gemm_d2_kernel<true, true, false><<<dim3(4096 / 128, MROWS / 128), 256, 0, stream>>>(
        n2, w1t, b1, nullptr, ff1, MROWS, 4096, 1024, 1024);
    gemm_d2_kernel<false, true, true><<<dim3(1024 / 128, MROWS / 128, 4), 256, 0, stream>>>(
        ff1, w2t, nullptr, nullptr, partials, MROWS, 1024, 1024, 4096);
    ff2_reduce_kernel<<<MROWS * DIMD / 1024, 256, 0, stream>>>(partials, x1, b2, out);
}